// Round 10
// baseline (123.865 us; speedup 1.0000x reference)
//
#include <hip/hip_runtime.h>
#include <hip/hip_bf16.h>

// out[b,i] = sum_{j<=i} x[b,j] * kernel[i-j]   (causal Toeplitz matmul)
// M=2048, N=K=4096. f32 in/out, bf16 MFMA compute.
//
// R15: col-split uniform blocks -> 4-fm B reuse. R13/R14 showed the LDS port
// is the binding constraint (64-row tiles: B-reads/MFMA = 1/2 -> 128 reads
// vs 1240cyc matrix per CU-step; R14's prefetch was neutral = throughput-
// bound signature). Now each of the 512 uniform 33-step blocks = 128 rows x
// one 64-COL half of ct-pair {31-ctp, ctp} (jj bit5 = col half). Waves per
// group: 2wm x 2wn -> 64 rows (fm=4) x 32 cols (fn=2) per wave: B-reads/MFMA
// = 1/4, port traffic HALVES (64 reads/CU-step ~1030cyc incl conflicts) while
// matrix stays 256 MFMA (~1240cyc) -> matrix-bound with 16 waves/CU. B window
// is K-range dominated so LDS barely grows: stride = 128(ct+1)+72 (==8 mod
// 64, same a*16B bank-phase trick), stride1+stride2 = 4368 -> 69888 B/block,
// 2 blocks/CU. Combine now 2 rounds x 4 f32x4 (slot-5, 20.5KB <= min 35.9KB
// phase-1 region). Co-resident pair (b,b+256) shares panel AND ct-pair (col
// halves differ) -> A lines shared in L1/L2. Whole-window prologue staging,
// barrier-free main loop, 1-step A prefetch, XCD panel affinity: unchanged.

typedef unsigned short u16;
typedef __attribute__((ext_vector_type(8))) short  bf16x8;
typedef __attribute__((ext_vector_type(8))) unsigned short u16x8;
typedef __attribute__((ext_vector_type(4))) float  f32x4;

#define KDIM 4096
#define NDIM 4096
#define MDIM 2048
#define KREV_STRIDE 4608                    // elems per shifted copy (global)
#define KREV_BYTES  (8 * KREV_STRIDE * 2)   // 73728

#define MFMA_BF16 __builtin_amdgcn_mfma_f32_16x16x32_bf16

static __device__ inline u16 f2bf(float f) {
  unsigned u = __builtin_bit_cast(unsigned, f);
  unsigned r = u + 0x7FFFu + ((u >> 16) & 1u);
  return (u16)(r >> 16);
}

static __device__ inline void async_copy16(const void* g, void* l) {
  __builtin_amdgcn_global_load_lds((const __attribute__((address_space(1))) void*)g,
                                   (__attribute__((address_space(3))) void*)l,
                                   16, 0, 0);
}

// Fused prep: blocks [0, conv_blocks) convert x->bf16 into the fragment-tiled
// layout; last 18 blocks build 8 shifted krev copies.
// Tiled layout: elem index = (rg*128 + kb)*512 + l*8 + e, where the 8 elems e
// are x[row = rg*16 + (l&15)][k = kb*32 + (l>>4)*8 + e]. One wave's fragment
// load (fixed rg,kb; l=lane) is 1KB contiguous.
__global__ __launch_bounds__(256) void prep(const float* __restrict__ x,
                                            const float* __restrict__ kern,
                                            u16* __restrict__ xb,
                                            u16* __restrict__ krevs,
                                            int conv_blocks) {
  int kblk = (int)blockIdx.x - conv_blocks;
  if (kblk >= 0) {
    int u = kblk * 256 + threadIdx.x;
    for (int a = 0; a < 8; ++a) {
      int t = u + a - 8;
      u16 v = 0;
      if (t >= 0 && t <= 4095) v = f2bf(kern[4095 - t]);
      krevs[a * KREV_STRIDE + u] = v;
    }
  } else {
    unsigned tg  = blockIdx.x * 256 + threadIdx.x;   // 0..2048*4096/8-1
    unsigned l   = tg & 63;
    unsigned kb  = (tg >> 6) & 127;
    unsigned rg  = tg >> 13;                         // 0..127
    unsigned row = rg * 16 + (l & 15);
    unsigned k   = kb * 32 + (l >> 4) * 8;
    const f32x4* p = (const f32x4*)(x + (size_t)row * KDIM + k);
    f32x4 v0 = p[0], v1 = p[1];
    u16x8 r;
    r[0] = f2bf(v0[0]); r[1] = f2bf(v0[1]); r[2] = f2bf(v0[2]); r[3] = f2bf(v0[3]);
    r[4] = f2bf(v1[0]); r[5] = f2bf(v1[1]); r[6] = f2bf(v1[2]); r[7] = f2bf(v1[3]);
    *(u16x8*)(xb + (size_t)tg * 8) = r;              // coalesced 1KB/wave
  }
}

template <bool CONV>
__global__ __launch_bounds__(512, 4) void toeplitz_gemm(const void* __restrict__ Av,
                                                        const u16* __restrict__ krevs,
                                                        float* __restrict__ out) {
  // LDS: two B windows, 8 copies each, stride_q = 128(ctq+1)+72 elems
  // (==8 mod 64); stride1+stride2 = 128*33+144 = 4368 -> 69888 B fixed.
  // Phase-1 region (8*stride1*2 >= 35968 B, dead after phase-1 compute)
  // hosts the 20480 B combine overlay; phase-2 region stays intact.
  __shared__ __align__(16) char smem_raw[69888];
  u16*   B_all = (u16*)smem_raw;
  f32x4* ep    = (f32x4*)smem_raw;            // combine overlay, 5 f32x4/slot

  const int tid  = threadIdx.x;
  const int w    = tid >> 6;        // 0..7
  const int g    = w >> 2;          // K-group 0..1
  const int wl   = w & 3;           // wave-in-group
  const int lane = tid & 63;
  const int lane16 = lane & 15;
  const int quad   = lane >> 4;
  const int wm = wl >> 1;           // 64-row half
  const int wn = wl & 1;            // 32-col half

  // XCD-affine uniform mapping: XCD x_=b&7 owns 128-row panels {x_, x_+8};
  // jj bits: 0 = panel parity, 1..4 = ctp, 5 = col half. Every block = 128
  // rows x 64-col half of pair {31-ctp, ctp} = 33 K-steps (uniform).
  // Co-resident pair (b, b+256): same panel, same ctp, other col half.
  const int b   = (int)blockIdx.x;
  const int x_  = b & 7;
  const int jj  = b >> 3;                 // 0..63 within XCD
  const int p_  = x_ + 8 * (jj & 1);      // 128-row panel 0..15
  const int ctp = (jj >> 1) & 15;
  const int cn  = jj >> 5;                // col half 0..1
  const int ct1 = 31 - ctp;               // phase 1 (big, >=16)
  const int ct2 = ctp;                    // phase 2
  const int m0  = p_ * 128;

  const int stride1 = 128 * (ct1 + 1) + 72;   // == staged len, ==8 mod 64
  const int stride2 = 128 * (ct2 + 1) + 72;
  const int base2   = 8 * stride1;            // elems
  const int W1 = 4032 - (ct1 * 128 + cn * 64);
  const int W2 = 4032 - (ct2 * 128 + cn * 64);

  // A addressing (R11): SGPR-ized; elem(fm,t,kk) =
  // (p_*8 + wm*4 + fm)*65536 + g*1024 + t*2048 + kk*512 + lane*8.
  const int wmu = __builtin_amdgcn_readfirstlane(wm);
  const int gu  = __builtin_amdgcn_readfirstlane(g);
  const u16*   xb2 = (const u16*)Av;
  const float* xf  = (const float*)Av;
  int aoffs[4];
  for (int fm = 0; fm < 4; ++fm)
    aoffs[fm] = (p_ * 8 + wmu * 4 + fm) * 65536 + gu * 1024 + lane * 8;
  const int rowb = m0 + wm * 64 + lane16;   // CONV source row base

  auto ldA = [&](int fm, int t, int kk) -> bf16x8 {
    return *(const bf16x8*)(xb2 + aoffs[fm] + t * 2048 + kk * 512);
  };
  auto ldAc = [&](int fm, int t, int kk) -> bf16x8 {
    const float* px = xf + (size_t)(rowb + fm * 16) * KDIM +
                      t * 128 + gu * 64 + kk * 32 + quad * 8;
    f32x4 v0 = *(const f32x4*)px, v1 = *(const f32x4*)(px + 4);
    u16x8 r;
    r[0]=f2bf(v0[0]); r[1]=f2bf(v0[1]); r[2]=f2bf(v0[2]); r[3]=f2bf(v0[3]);
    r[4]=f2bf(v1[0]); r[5]=f2bf(v1[1]); r[6]=f2bf(v1[2]); r[7]=f2bf(v1[3]);
    return __builtin_bit_cast(bf16x8, r);
  };

  // ---- prologue: stage BOTH B windows (wave w stages copy w) ----
  auto stageWin = [&](int base_e, int stride_e, int Wp) {
    const u16* src = krevs + w * KREV_STRIDE + Wp;
    char* dstb = smem_raw + (size_t)(base_e + w * stride_e) * 2;
    for (int c = 0; c * 512 < stride_e; ++c) {
      int idx = c * 512 + lane * 8;
      if (idx < stride_e)
        async_copy16(src + idx, dstb + (size_t)c * 1024);
    }
  };
  stageWin(0, stride1, W1);
  stageWin(base2, stride2, W2);
  asm volatile("s_waitcnt vmcnt(0)" ::: "memory");
  __builtin_amdgcn_s_barrier();
  asm volatile("" ::: "memory");

  // ---- one phase: barrier-free K loop + 2-round combine + epilogue ----
  auto runPhase = [&](int ctq, int base_e, int stride_q, int Wq) {
    const int n0c = ctq * 128 + cn * 64;
    int boff[2];
    for (int fn = 0; fn < 2; ++fn) {
      int n_g = n0c + wn * 32 + fn * 16 + lane16;
      int s0  = 4095 - n_g + quad * 8;
      int a   = s0 & 7;
      boff[fn] = base_e + a * stride_q + (s0 - a + 8 - Wq);
    }
    f32x4 acc[4][2] = {};

    if constexpr (!CONV) {
      bf16x8 afA[4], afB[4];
#pragma unroll
      for (int fm = 0; fm < 4; ++fm) afA[fm] = ldA(fm, 0, 0);
#pragma unroll
      for (int fm = 0; fm < 4; ++fm) afB[fm] = ldA(fm, 0, 1);
      for (int t = 0; ; ++t) {
        const int ks = t * 128 + g * 64;
#pragma unroll
        for (int fn = 0; fn < 2; ++fn) {
          bf16x8 bv = *(const bf16x8*)(&B_all[boff[fn] + ks]);
#pragma unroll
          for (int fm = 0; fm < 4; ++fm)
            acc[fm][fn] = MFMA_BF16(afA[fm], bv, acc[fm][fn], 0, 0, 0);
        }
        if (t < ctq)
#pragma unroll
          for (int fm = 0; fm < 4; ++fm) afA[fm] = ldA(fm, t + 1, 0);
#pragma unroll
        for (int fn = 0; fn < 2; ++fn) {
          bf16x8 bv = *(const bf16x8*)(&B_all[boff[fn] + ks + 32]);
#pragma unroll
          for (int fm = 0; fm < 4; ++fm)
            acc[fm][fn] = MFMA_BF16(afB[fm], bv, acc[fm][fn], 0, 0, 0);
        }
        if (t == ctq) break;
#pragma unroll
        for (int fm = 0; fm < 4; ++fm) afB[fm] = ldA(fm, t + 1, 1);
      }
    } else {
      for (int t = 0; t <= ctq; ++t) {
        const int ks = t * 128 + g * 64;
#pragma unroll
        for (int kk = 0; kk < 2; ++kk) {
          bf16x8 af[4];
#pragma unroll
          for (int fm = 0; fm < 4; ++fm) af[fm] = ldAc(fm, t, kk);
#pragma unroll
          for (int fn = 0; fn < 2; ++fn) {
            bf16x8 bv = *(const bf16x8*)(&B_all[boff[fn] + ks + kk * 32]);
#pragma unroll
            for (int fm = 0; fm < 4; ++fm)
              acc[fm][fn] = MFMA_BF16(af[fm], bv, acc[fm][fn], 0, 0, 0);
          }
        }
      }
    }

    // combine (2 rounds x 4 f32x4, slot stride 5 -> 20480 B overlay in the
    // phase-1 region) + epilogue. g1 ships partials, g0 adds and stores.
    const int j = tid & 255;
    __syncthreads();                       // all compute on this phase done
#pragma unroll
    for (int r = 0; r < 2; ++r) {
      if (r) __syncthreads();              // round-0 slots free
      if (g == 1) {
        for (int fm2 = 0; fm2 < 2; ++fm2)
          for (int fn = 0; fn < 2; ++fn)
            ep[j * 5 + fm2 * 2 + fn] = acc[r * 2 + fm2][fn];
      }
      __syncthreads();
      if (g == 0) {
        for (int fm2 = 0; fm2 < 2; ++fm2)
          for (int fn = 0; fn < 2; ++fn) {
            f32x4 v = acc[r * 2 + fm2][fn];
            f32x4 o = ep[j * 5 + fm2 * 2 + fn];
            v[0] += o[0]; v[1] += o[1]; v[2] += o[2]; v[3] += o[3];
            int fm = r * 2 + fm2;
            int row_base = m0 + wm * 64 + fm * 16 + quad * 4;
            int col = n0c + wn * 32 + fn * 16 + lane16;
            for (int rr = 0; rr < 4; ++rr)
              out[(size_t)(row_base + rr) * NDIM + col] = v[rr];
          }
      }
    }
  };

  runPhase(ct1, 0, stride1, W1);       // big phase first (region >= 35968 B)
  runPhase(ct2, base2, stride2, W2);   // its window untouched by the overlay
}

extern "C" void kernel_launch(void* const* d_in, const int* in_sizes, int n_in,
                              void* d_out, int out_size, void* d_ws, size_t ws_size,
                              hipStream_t stream) {
  const float* x    = (const float*)d_in[0];
  const float* kern = (const float*)d_in[1];
  float* out = (float*)d_out;

  u16* krevs = (u16*)d_ws;
  u16* xb    = (u16*)((char*)d_ws + KREV_BYTES);
  const size_t need_fast = (size_t)KREV_BYTES + (size_t)MDIM * KDIM * 2;

  if (ws_size >= need_fast) {
    prep<<<4096 + 18, 256, 0, stream>>>(x, kern, xb, krevs, 4096);
    toeplitz_gemm<false><<<512, 512, 0, stream>>>(xb, krevs, out);
  } else {
    prep<<<18, 256, 0, stream>>>(x, kern, xb, krevs, 0);
    toeplitz_gemm<true><<<512, 512, 0, stream>>>(x, krevs, out);
  }
}